// Round 1
// baseline (416.095 us; speedup 1.0000x reference)
//
#include <hip/hip_runtime.h>

#define HW    12288
#define Wimg  192
#define Himg  64
#define Wpad  194
#define Ppad  12804   // 66*194

typedef __attribute__((ext_vector_type(8))) __bf16 bf16x8;
typedef __attribute__((ext_vector_type(4))) float  f32x4;

// bf16 <-> fp32 helpers (RNE), header-independent
static __device__ __forceinline__ unsigned short f2bf(float f) {
    union { float f; unsigned int u; } v; v.f = f;
    unsigned int r = v.u + 0x7fffu + ((v.u >> 16) & 1u);
    return (unsigned short)(r >> 16);
}
static __device__ __forceinline__ float bf2f(unsigned short h) {
    union { unsigned int u; float f; } v; v.u = ((unsigned int)h) << 16;
    return v.f;
}
static __device__ __forceinline__ float bflo(unsigned int u) {
    union { unsigned int u; float f; } v; v.u = u << 16; return v.f;
}
static __device__ __forceinline__ float bfhi(unsigned int u) {
    union { unsigned int u; float f; } v; v.u = u & 0xffff0000u; return v.f;
}
static __device__ __forceinline__ __bf16 us2bf(unsigned short u) {
    union { unsigned short u; __bf16 b; } v; v.u = u; return v.b;
}

// ---------------------------------------------------------------------------
// K1: deformable gather via LDS-staged windows (flat-space staging).
// Unchanged math (R15-R19 proven).  R20: also zeroes the 3 psum arrays
// (block (0,0)) so the fused-stats GEMMs can atomicAdd into them.
// ---------------------------------------------------------------------------
__global__ __launch_bounds__(256, 6) void k_deform(
    const float* __restrict__ x,     // 256 x HW
    const float* __restrict__ xr,    // HW
    const float* __restrict__ rout,  // 256 x 9
    unsigned short* __restrict__ y0, // 256 x HW (bf16)
    float* __restrict__ psz)         // 3 x 256 floats to zero
{
    __shared__ unsigned short s_x[32][240];  // 3 window rows x stride 80

    if (blockIdx.x == 0 && blockIdx.y == 0) {
        psz[threadIdx.x]       = 0.0f;
        psz[threadIdx.x + 256] = 0.0f;
        psz[threadIdx.x + 512] = 0.0f;
    }

    const int cblk = blockIdx.x;     // 0..7   (fastest -> XCD id)
    const int tile = blockIdx.y;     // 0..191
    const int tid  = threadIdx.x;
    const int pl   = tid & 63;
    const int wv   = __builtin_amdgcn_readfirstlane(tid >> 6);
    const int h    = tile / 3;
    const int w0   = (tile - h * 3) * 64;
    const int w    = w0 + pl;
    const int gp   = h * Wimg + w;

    int   li[6];
    float gw[6][3];
    const float off = 3.0f / (1.0f + expf(-xr[gp]));

    #pragma unroll
    for (int t = 0; t < 6; ++t) {
        const int xo = (t & 1) ? 1 : -1;
        const int yo = (t >> 1) - 1;
        float ov  = off * (float)xo;
        int   iv  = yo * Wpad;
        int   pre = (h + 1) * Wpad + (w + 1) + xo + iv;
        float after = (float)(pre + iv) + ov;
        int fl = (int)floorf(ov);
        int ce = (int)ceilf(ov);
        int av_f  = min(max(pre + fl + iv, 0), Ppad - 1);
        int av_f1 = min(max(av_f + xo,    0), Ppad - 1);
        int av_c  = min(max(pre + ce + iv, 0), Ppad - 1);
        int av_c1 = min(max(av_c + xo,    0), Ppad - 1);
        float wf  = fabsf(after - (float)av_f);
        float wf1 = fabsf((float)av_f1 - after);
        float wc1 = fabsf(after - (float)av_c1);
        float wc  = fabsf((float)av_c - after);
        float s1 = wf  * (1.0f / Wpad);
        float s2 = wc1 * (1.0f / Wpad);
        int   i4[4] = { av_f, av_f1, av_c1, av_c };
        float w4[4] = { s1 * wf, s1 * wf1, s2 * wc1, s2 * wc };
        int b = min(min(i4[0], i4[1]), min(i4[2], i4[3]));
        const int base = (h + 1 + 2 * yo) * Wpad + w0 - 4;
        li[t] = (t >> 1) * 80 + min(max(b - base, 0), 71);
        #pragma unroll
        for (int s = 0; s < 3; ++s) {
            float ws = 0.0f;
            #pragma unroll
            for (int j = 0; j < 4; ++j)
                ws += (i4[j] == b + s) ? w4[j] : 0.0f;
            int av = b + s;
            int r  = av / Wpad;
            int cc = av - r * Wpad;
            bool inb = (r >= 1) && (r <= Himg) && (cc >= 1) && (cc <= Wimg);
            gw[t][s] = inb ? ws : 0.0f;
        }
    }

    // stage the 3x74 flat windows for the block's 32 channels (bf16)
    const int jj = tid;
    int  xoff = 0;
    bool valid = false;
    int  rr = 0, jcol = 0;
    if (jj < 222) {
        rr   = jj / 74;
        jcol = jj - rr * 74;
        const int flat = (h + 1 + 2 * (rr - 1)) * Wpad + w0 - 4 + jcol;
        if (flat >= 0 && flat < Ppad) {
            const int r = flat / Wpad;
            const int c = flat - r * Wpad;
            valid = (r >= 1) && (r <= Himg) && (c >= 1) && (c <= Wimg);
            xoff  = valid ? ((r - 1) * Wimg + (c - 1)) : 0;
        }
    }
    const float* xb = x + (size_t)(cblk * 32) * HW;
    for (int c = 0; c < 32; ++c) {
        if (jj < 222) {
            float v = valid ? xb[(size_t)c * HW + xoff] : 0.0f;
            s_x[c][rr * 80 + jcol] = f2bf(v);
        }
    }
    __syncthreads();

    const int c0l = wv * 8;
    #pragma unroll 2
    for (int i = 0; i < 8; ++i) {
        const int cl = c0l + i;
        const unsigned short* sxc = s_x[cl];
        const float* rc = rout + (cblk * 32 + cl) * 9;
        float acc = 0.0f;
        #pragma unroll
        for (int t = 0; t < 6; ++t) {
            float part = gw[t][0] * bf2f(sxc[li[t]])
                       + gw[t][1] * bf2f(sxc[li[t] + 1])
                       + gw[t][2] * bf2f(sxc[li[t] + 2]);
            const int k = 3 * (t >> 1) + ((t & 1) ? 2 : 0);
            acc += rc[k] * part;
        }
        y0[(size_t)(cblk * 32 + cl) * HW + gp] = f2bf(acc);
    }
}

// ---------------------------------------------------------------------------
// R20: MFMA pointwise GEMM (bf16), no split-K, fused BN-stats epilogue.
//   Z[o][p] = sum_c W[o][c] * A[c][p],  o in [0,128), p tile = 32 px.
// A operand = weights (hi+lo bf16 split -> fp32-equivalent precision),
// B operand = acts, staged transposed to LDS s_b[px][c] with XOR swizzle
// (c ^= ((p>>4)&3)<<3) so B-fragments are conflict-free ds_read_b128.
// Epilogue: store bf16 Z + per-channel {sum, sumsq} via shfl-reduce +
// atomicAdd (psum pre-zeroed by k_deform).
// Block: 4 waves x (16 o x 32 px).  Grid (384 px-blocks, 2 o-blocks) = 768.
// ---------------------------------------------------------------------------
template <int CIN>
__global__ __launch_bounds__(256) void k_pw_mfma(
    const unsigned short* __restrict__ Aact,  // CIN x HW (bf16)
    const float* __restrict__ Wm,             // 128 x CIN (fp32)
    unsigned short* __restrict__ Z,           // 128 x HW (bf16)
    float* __restrict__ psum)                 // 128 x {sum, sumsq}
{
    constexpr int KC = CIN / 32;
    constexpr int RS = CIN + 8;               // pad keeps b128 16B-aligned, 2-way banks
    __shared__ __align__(16) unsigned short s_b[32][RS];

    const int tid = threadIdx.x;
    const int l   = tid & 63;
    const int wv  = tid >> 6;
    const int px0 = blockIdx.x * 32;
    const int o0  = blockIdx.y * 64;

    // ---- stage act tile transposed: s_b[p][c ^ (((p>>4)&3)<<3)] ----
    {
        const int cs  = tid >> 1;             // 0..127
        const int pxb = (tid & 1) << 4;       // 0 or 16
        const int swz = (tid & 1) << 3;       // (p>>4)&3 == tid&1 here
        #pragma unroll
        for (int it = 0; it < CIN / 128; ++it) {
            const int c = cs + it * 128;
            const uint4* src = (const uint4*)(Aact + (size_t)c * HW + px0 + pxb);
            uint4 u0 = src[0];
            uint4 u1 = src[1];
            const int sc = c ^ swz;
            unsigned int wd[8] = {u0.x, u0.y, u0.z, u0.w, u1.x, u1.y, u1.z, u1.w};
            #pragma unroll
            for (int e = 0; e < 8; ++e) {
                s_b[pxb + 2 * e    ][sc] = (unsigned short)(wd[e] & 0xffffu);
                s_b[pxb + 2 * e + 1][sc] = (unsigned short)(wd[e] >> 16);
            }
        }
    }

    // ---- preload weight fragments (hi/lo bf16 split), overlaps staging ----
    // A-frag layout: row m = l&15, k = (l>>4)*8 + j  (matrix-calculator conv.)
    bf16x8 wh[KC], wl[KC];
    {
        const int orow = o0 + wv * 16 + (l & 15);
        const float* wp = Wm + (size_t)orow * CIN + ((l >> 4) << 3);
        #pragma unroll
        for (int kc = 0; kc < KC; ++kc) {
            #pragma unroll
            for (int j = 0; j < 8; ++j) {
                float f = wp[kc * 32 + j];
                unsigned short hu = f2bf(f);
                unsigned short lu = f2bf(f - bf2f(hu));
                wh[kc][j] = us2bf(hu);
                wl[kc][j] = us2bf(lu);
            }
        }
    }
    __syncthreads();

    // ---- MFMA K-loop ----
    f32x4 acc[2] = { {0.f, 0.f, 0.f, 0.f}, {0.f, 0.f, 0.f, 0.f} };
    const int prow = l & 15;
    const int kg8  = l >> 4;
    #pragma unroll
    for (int kc = 0; kc < KC; ++kc) {
        #pragma unroll
        for (int ip = 0; ip < 2; ++ip) {
            const int col = kc * 32 + (((kg8 ^ ip) & 3) << 3);
            bf16x8 bfr = *(const bf16x8*)&s_b[ip * 16 + prow][col];
            acc[ip] = __builtin_amdgcn_mfma_f32_16x16x32_bf16(wh[kc], bfr, acc[ip], 0, 0, 0);
            acc[ip] = __builtin_amdgcn_mfma_f32_16x16x32_bf16(wl[kc], bfr, acc[ip], 0, 0, 0);
        }
    }

    // ---- epilogue: store Z (bf16) + fused BN stats ----
    // D layout: col = l&15 (px), row m = (l>>4)*4 + r  (m89-verified)
    const int obase = o0 + wv * 16 + ((l >> 4) << 2);
    #pragma unroll
    for (int r = 0; r < 4; ++r) {
        const int ch = obase + r;
        float v0 = acc[0][r];
        float v1 = acc[1][r];
        Z[(size_t)ch * HW + px0 + prow]      = f2bf(v0);
        Z[(size_t)ch * HW + px0 + 16 + prow] = f2bf(v1);
        float s = v0 + v1;
        float q = v0 * v0 + v1 * v1;
        s += __shfl_xor(s, 1, 64);  q += __shfl_xor(q, 1, 64);
        s += __shfl_xor(s, 2, 64);  q += __shfl_xor(q, 2, 64);
        s += __shfl_xor(s, 4, 64);  q += __shfl_xor(q, 4, 64);
        s += __shfl_xor(s, 8, 64);  q += __shfl_xor(q, 8, 64);
        if (prow == 0) {
            atomicAdd(&psum[2 * ch],     s);
            atomicAdd(&psum[2 * ch + 1], q);
        }
    }
}

// ---------------------------------------------------------------------------
// Fused: BN+LeakyReLU + depthwise 3x3 (zero pad), single-Z input.
// ---------------------------------------------------------------------------
__global__ __launch_bounds__(256) void k_dw(
    const unsigned short* __restrict__ Zs,
    const float* __restrict__ psum,  // 128 x {sum,sumsq}
    const float* __restrict__ g,
    const float* __restrict__ b,
    const float* __restrict__ dwgt,  // 128 x 9
    ushort4* __restrict__ D)
{
    const int t  = blockIdx.x * 256 + threadIdx.x;  // 0..393215
    const int c  = t / 3072;
    const int gg = t - c * 3072;
    const int h  = gg / 48;
    const int w0 = (gg - h * 48) << 2;

    const float s   = psum[2 * c];
    const float q   = psum[2 * c + 1];
    const float mu  = s * (1.0f / HW);
    const float var = q * (1.0f / HW) - mu * mu;
    const float sc  = g[c] * rsqrtf(var + 1e-5f);
    const float sh  = b[c] - mu * sc;

    float wk[9];
    #pragma unroll
    for (int k = 0; k < 9; ++k) wk[k] = dwgt[c * 9 + k];

    const unsigned short* z0 = Zs + (size_t)c * HW;
    float v[3][6];
    #pragma unroll
    for (int ky = 0; ky < 3; ++ky) {
        const int hh  = h + ky - 1;
        const bool rin = (hh >= 0) && (hh < Himg);
        #pragma unroll
        for (int j = 0; j < 6; ++j) {
            const int ww = w0 - 1 + j;
            const bool in = rin && (ww >= 0) && (ww < Wimg);
            float z = in ? bf2f(z0[hh * Wimg + ww]) : 0.0f;
            float y = z * sc + sh;
            y = (y >= 0.0f) ? y : 0.01f * y;
            v[ky][j] = in ? y : 0.0f;
        }
    }

    ushort4 o;
    float oo[4];
    #pragma unroll
    for (int j = 0; j < 4; ++j) {
        float a = 0.0f;
        #pragma unroll
        for (int ky = 0; ky < 3; ++ky)
            #pragma unroll
            for (int kx = 0; kx < 3; ++kx)
                a += wk[ky * 3 + kx] * v[ky][j + kx];
        oo[j] = a;
    }
    o.x = f2bf(oo[0]); o.y = f2bf(oo[1]); o.z = f2bf(oo[2]); o.w = f2bf(oo[3]);
    D[t] = o;
}

// ---------------------------------------------------------------------------
// Final: BN+LeakyReLU, fp32 out, single-Z input.  grid = 1536.
// ---------------------------------------------------------------------------
__global__ __launch_bounds__(256) void k_final(
    const unsigned short* __restrict__ Zs,
    const float* __restrict__ psum,
    const float* __restrict__ g,
    const float* __restrict__ b,
    float4* __restrict__ out)
{
    const int f = blockIdx.x * 256 + threadIdx.x;
    const int c = f / 3072;

    const float s   = psum[2 * c];
    const float q   = psum[2 * c + 1];
    const float mu  = s * (1.0f / HW);
    const float var = q * (1.0f / HW) - mu * mu;
    const float sc  = g[c] * rsqrtf(var + 1e-5f);
    const float sh  = b[c] - mu * sc;

    uint2 a = ((const uint2*)Zs)[f];
    float4 v;
    v.x = bflo(a.x) * sc + sh; v.x = (v.x >= 0.0f) ? v.x : 0.01f * v.x;
    v.y = bfhi(a.x) * sc + sh; v.y = (v.y >= 0.0f) ? v.y : 0.01f * v.y;
    v.z = bflo(a.y) * sc + sh; v.z = (v.z >= 0.0f) ? v.z : 0.01f * v.z;
    v.w = bfhi(a.y) * sc + sh; v.w = (v.w >= 0.0f) ? v.w : 0.01f * v.w;
    out[f] = v;
}

// ---------------------------------------------------------------------------
extern "C" void kernel_launch(void* const* d_in, const int* in_sizes, int n_in,
                              void* d_out, int out_size, void* d_ws, size_t ws_size,
                              hipStream_t stream) {
    const float* x   = (const float*)d_in[0];
    const float* xr  = (const float*)d_in[1];
    const float* ro  = (const float*)d_in[2];
    const float* wr  = (const float*)d_in[3];
    const float* gr  = (const float*)d_in[4];
    const float* br  = (const float*)d_in[5];
    const float* dw1 = (const float*)d_in[6];
    const float* pw1 = (const float*)d_in[7];
    const float* g1  = (const float*)d_in[8];
    const float* b1  = (const float*)d_in[9];
    const float* dw2 = (const float*)d_in[10];
    const float* pw2 = (const float*)d_in[11];
    const float* g2  = (const float*)d_in[12];
    const float* b2  = (const float*)d_in[13];

    unsigned short* WS = (unsigned short*)d_ws;
    unsigned short* y0 = WS;                  // 256 x HW bf16
    unsigned short* Z1 = WS + 3145728;        // 128 x HW bf16
    unsigned short* D  = WS + 4718592;        // 128 x HW bf16 (dw out, reused)
    unsigned short* Z2 = WS + 6291456;
    unsigned short* Z3 = WS + 7864320;
    float* p1 = (float*)(WS + 9437184);       // 3 x 256 floats {sum,sumsq}
    float* p2 = p1 + 256;
    float* p3 = p2 + 256;
    float* out = (float*)d_out;

    k_deform<<<dim3(8, 192), 256, 0, stream>>>(x, xr, ro, y0, p1);
    k_pw_mfma<256><<<dim3(384, 2), 256, 0, stream>>>(y0, wr, Z1, p1);
    k_dw<<<1536, 256, 0, stream>>>(Z1, p1, gr, br, dw1, (ushort4*)D);
    k_pw_mfma<128><<<dim3(384, 2), 256, 0, stream>>>(D, pw1, Z2, p2);
    k_dw<<<1536, 256, 0, stream>>>(Z2, p2, g1, b1, dw2, (ushort4*)D);
    k_pw_mfma<128><<<dim3(384, 2), 256, 0, stream>>>(D, pw2, Z3, p3);
    k_final<<<1536, 256, 0, stream>>>(Z3, p3, g2, b2, (float4*)out);
}

// Round 2
// 400.966 us; speedup vs baseline: 1.0377x; 1.0377x over previous
//
#include <hip/hip_runtime.h>

#define HW    12288
#define Wimg  192
#define Himg  64
#define Wpad  194
#define Ppad  12804   // 66*194

typedef __attribute__((ext_vector_type(8))) __bf16 bf16x8;
typedef __attribute__((ext_vector_type(4))) float  f32x4;

// bf16 <-> fp32 helpers (RNE), header-independent
static __device__ __forceinline__ unsigned short f2bf(float f) {
    union { float f; unsigned int u; } v; v.f = f;
    unsigned int r = v.u + 0x7fffu + ((v.u >> 16) & 1u);
    return (unsigned short)(r >> 16);
}
static __device__ __forceinline__ float bf2f(unsigned short h) {
    union { unsigned int u; float f; } v; v.u = ((unsigned int)h) << 16;
    return v.f;
}
static __device__ __forceinline__ float bflo(unsigned int u) {
    union { unsigned int u; float f; } v; v.u = u << 16; return v.f;
}
static __device__ __forceinline__ float bfhi(unsigned int u) {
    union { unsigned int u; float f; } v; v.u = u & 0xffff0000u; return v.f;
}

// ---------------------------------------------------------------------------
// R21: weight prep — fp32 W -> bf16 hi/lo pair (fp32-equivalent precision in
// the 2-MFMA scheme), plus psum zeroing.  Runs once, ~65k elements.
// ---------------------------------------------------------------------------
__global__ __launch_bounds__(256) void k_wprep(
    const float* __restrict__ wr,    // 128 x 256
    const float* __restrict__ pw1,   // 128 x 128
    const float* __restrict__ pw2,   // 128 x 128
    unsigned short* __restrict__ W1h, unsigned short* __restrict__ W1l,
    unsigned short* __restrict__ W2h, unsigned short* __restrict__ W2l,
    unsigned short* __restrict__ W3h, unsigned short* __restrict__ W3l,
    float* __restrict__ psz)         // 3 x 256 floats to zero
{
    const int idx = blockIdx.x * 256 + threadIdx.x;
    if (blockIdx.x == 0) {
        psz[threadIdx.x]       = 0.0f;
        psz[threadIdx.x + 256] = 0.0f;
        psz[threadIdx.x + 512] = 0.0f;
    }
    float v;
    unsigned short *dh, *dl;
    if (idx < 32768)      { v = wr[idx];          dh = W1h + idx; dl = W1l + idx; }
    else if (idx < 49152) { int t = idx - 32768;  v = pw1[t]; dh = W2h + t; dl = W2l + t; }
    else                  { int t = idx - 49152;  v = pw2[t]; dh = W3h + t; dl = W3l + t; }
    unsigned short h = f2bf(v);
    *dh = h;
    *dl = f2bf(v - bf2f(h));
}

// ---------------------------------------------------------------------------
// K1: deformable gather via LDS-staged windows (flat-space staging).
// Unchanged math (R15-R19 proven).
// ---------------------------------------------------------------------------
__global__ __launch_bounds__(256, 6) void k_deform(
    const float* __restrict__ x,     // 256 x HW
    const float* __restrict__ xr,    // HW
    const float* __restrict__ rout,  // 256 x 9
    unsigned short* __restrict__ y0) // 256 x HW (bf16)
{
    __shared__ unsigned short s_x[32][240];  // 3 window rows x stride 80

    const int cblk = blockIdx.x;     // 0..7   (fastest -> XCD id)
    const int tile = blockIdx.y;     // 0..191
    const int tid  = threadIdx.x;
    const int pl   = tid & 63;
    const int wv   = __builtin_amdgcn_readfirstlane(tid >> 6);
    const int h    = tile / 3;
    const int w0   = (tile - h * 3) * 64;
    const int w    = w0 + pl;
    const int gp   = h * Wimg + w;

    int   li[6];
    float gw[6][3];
    const float off = 3.0f / (1.0f + expf(-xr[gp]));

    #pragma unroll
    for (int t = 0; t < 6; ++t) {
        const int xo = (t & 1) ? 1 : -1;
        const int yo = (t >> 1) - 1;
        float ov  = off * (float)xo;
        int   iv  = yo * Wpad;
        int   pre = (h + 1) * Wpad + (w + 1) + xo + iv;
        float after = (float)(pre + iv) + ov;
        int fl = (int)floorf(ov);
        int ce = (int)ceilf(ov);
        int av_f  = min(max(pre + fl + iv, 0), Ppad - 1);
        int av_f1 = min(max(av_f + xo,    0), Ppad - 1);
        int av_c  = min(max(pre + ce + iv, 0), Ppad - 1);
        int av_c1 = min(max(av_c + xo,    0), Ppad - 1);
        float wf  = fabsf(after - (float)av_f);
        float wf1 = fabsf((float)av_f1 - after);
        float wc1 = fabsf(after - (float)av_c1);
        float wc  = fabsf((float)av_c - after);
        float s1 = wf  * (1.0f / Wpad);
        float s2 = wc1 * (1.0f / Wpad);
        int   i4[4] = { av_f, av_f1, av_c1, av_c };
        float w4[4] = { s1 * wf, s1 * wf1, s2 * wc1, s2 * wc };
        int b = min(min(i4[0], i4[1]), min(i4[2], i4[3]));
        const int base = (h + 1 + 2 * yo) * Wpad + w0 - 4;
        li[t] = (t >> 1) * 80 + min(max(b - base, 0), 71);
        #pragma unroll
        for (int s = 0; s < 3; ++s) {
            float ws = 0.0f;
            #pragma unroll
            for (int j = 0; j < 4; ++j)
                ws += (i4[j] == b + s) ? w4[j] : 0.0f;
            int av = b + s;
            int r  = av / Wpad;
            int cc = av - r * Wpad;
            bool inb = (r >= 1) && (r <= Himg) && (cc >= 1) && (cc <= Wimg);
            gw[t][s] = inb ? ws : 0.0f;
        }
    }

    // stage the 3x74 flat windows for the block's 32 channels (bf16)
    const int jj = tid;
    int  xoff = 0;
    bool valid = false;
    int  rr = 0, jcol = 0;
    if (jj < 222) {
        rr   = jj / 74;
        jcol = jj - rr * 74;
        const int flat = (h + 1 + 2 * (rr - 1)) * Wpad + w0 - 4 + jcol;
        if (flat >= 0 && flat < Ppad) {
            const int r = flat / Wpad;
            const int c = flat - r * Wpad;
            valid = (r >= 1) && (r <= Himg) && (c >= 1) && (c <= Wimg);
            xoff  = valid ? ((r - 1) * Wimg + (c - 1)) : 0;
        }
    }
    const float* xb = x + (size_t)(cblk * 32) * HW;
    for (int c = 0; c < 32; ++c) {
        if (jj < 222) {
            float v = valid ? xb[(size_t)c * HW + xoff] : 0.0f;
            s_x[c][rr * 80 + jcol] = f2bf(v);
        }
    }
    __syncthreads();

    const int c0l = wv * 8;
    #pragma unroll 2
    for (int i = 0; i < 8; ++i) {
        const int cl = c0l + i;
        const unsigned short* sxc = s_x[cl];
        const float* rc = rout + (cblk * 32 + cl) * 9;
        float acc = 0.0f;
        #pragma unroll
        for (int t = 0; t < 6; ++t) {
            float part = gw[t][0] * bf2f(sxc[li[t]])
                       + gw[t][1] * bf2f(sxc[li[t] + 1])
                       + gw[t][2] * bf2f(sxc[li[t] + 2]);
            const int k = 3 * (t >> 1) + ((t & 1) ? 2 : 0);
            acc += rc[k] * part;
        }
        y0[(size_t)(cblk * 32 + cl) * HW + gp] = f2bf(acc);
    }
}

// ---------------------------------------------------------------------------
// R21: MFMA pointwise GEMM, loop-structured (no big live register arrays).
//   Z[o][p] = sum_c W[o][c] * A[c][p],  o in [0,128), p tile = 32 px.
// Weights pre-split to bf16 hi/lo by k_wprep -> one b128 load per fragment.
// B operand = acts staged transposed to LDS s_b[px][c], XOR swizzle
// (c ^= ((p>>4)&3)<<3).  Fused BN-stats epilogue (atomicAdd to psum).
// Block: 4 waves x (16 o x 32 px).  Grid (384 px-blocks, 2 o-blocks) = 768.
// ---------------------------------------------------------------------------
template <int CIN>
__global__ __launch_bounds__(256, 4) void k_pw_mfma(
    const unsigned short* __restrict__ Aact,  // CIN x HW (bf16)
    const unsigned short* __restrict__ Whi,   // 128 x CIN (bf16)
    const unsigned short* __restrict__ Wlo,   // 128 x CIN (bf16)
    unsigned short* __restrict__ Z,           // 128 x HW (bf16)
    float* __restrict__ psum)                 // 128 x {sum, sumsq}
{
    constexpr int KC = CIN / 32;
    constexpr int RS = CIN + 8;               // pad keeps b128 16B-aligned
    __shared__ __align__(16) unsigned short s_b[32][RS];

    const int tid = threadIdx.x;
    const int l   = tid & 63;
    const int wv  = tid >> 6;
    const int px0 = blockIdx.x * 32;
    const int o0  = blockIdx.y * 64;

    // ---- stage act tile transposed: s_b[p][c ^ (((p>>4)&3)<<3)] ----
    {
        const int cs  = tid >> 1;             // 0..127
        const int pxb = (tid & 1) << 4;       // 0 or 16
        const int swz = (tid & 1) << 3;       // (p>>4)&3 == tid&1 here
        #pragma unroll
        for (int it = 0; it < CIN / 128; ++it) {
            const int c = cs + it * 128;
            const uint4* src = (const uint4*)(Aact + (size_t)c * HW + px0 + pxb);
            uint4 u0 = src[0];
            uint4 u1 = src[1];
            const int sc = c ^ swz;
            unsigned int wd[8] = {u0.x, u0.y, u0.z, u0.w, u1.x, u1.y, u1.z, u1.w};
            #pragma unroll
            for (int e = 0; e < 8; ++e) {
                s_b[pxb + 2 * e    ][sc] = (unsigned short)(wd[e] & 0xffffu);
                s_b[pxb + 2 * e + 1][sc] = (unsigned short)(wd[e] >> 16);
            }
        }
    }

    // weight fragment base: row m = l&15, k-group = l>>4 (8 consecutive c)
    const int orow = o0 + wv * 16 + (l & 15);
    const unsigned short* whp = Whi + (size_t)orow * CIN + ((l >> 4) << 3);
    const unsigned short* wlp = Wlo + (size_t)orow * CIN + ((l >> 4) << 3);

    __syncthreads();

    // ---- MFMA K-loop: per kc = 2 weight b128 loads + 2 LDS b128 + 4 MFMA ----
    f32x4 acc[2] = { {0.f, 0.f, 0.f, 0.f}, {0.f, 0.f, 0.f, 0.f} };
    const int prow = l & 15;
    const int kg8  = l >> 4;
    #pragma unroll 4
    for (int kc = 0; kc < KC; ++kc) {
        bf16x8 wh = *(const bf16x8*)(whp + kc * 32);
        bf16x8 wl = *(const bf16x8*)(wlp + kc * 32);
        #pragma unroll
        for (int ip = 0; ip < 2; ++ip) {
            const int col = kc * 32 + (((kg8 ^ ip) & 3) << 3);
            bf16x8 bfr = *(const bf16x8*)&s_b[ip * 16 + prow][col];
            acc[ip] = __builtin_amdgcn_mfma_f32_16x16x32_bf16(wh, bfr, acc[ip], 0, 0, 0);
            acc[ip] = __builtin_amdgcn_mfma_f32_16x16x32_bf16(wl, bfr, acc[ip], 0, 0, 0);
        }
    }

    // ---- epilogue: store Z (bf16) + fused BN stats ----
    // D layout: col = l&15 (px), row m = (l>>4)*4 + r  (m89-verified)
    const int obase = o0 + wv * 16 + ((l >> 4) << 2);
    #pragma unroll
    for (int r = 0; r < 4; ++r) {
        const int ch = obase + r;
        float v0 = acc[0][r];
        float v1 = acc[1][r];
        Z[(size_t)ch * HW + px0 + prow]      = f2bf(v0);
        Z[(size_t)ch * HW + px0 + 16 + prow] = f2bf(v1);
        float s = v0 + v1;
        float q = v0 * v0 + v1 * v1;
        s += __shfl_xor(s, 1, 64);  q += __shfl_xor(q, 1, 64);
        s += __shfl_xor(s, 2, 64);  q += __shfl_xor(q, 2, 64);
        s += __shfl_xor(s, 4, 64);  q += __shfl_xor(q, 4, 64);
        s += __shfl_xor(s, 8, 64);  q += __shfl_xor(q, 8, 64);
        if (prow == 0) {
            atomicAdd(&psum[2 * ch],     s);
            atomicAdd(&psum[2 * ch + 1], q);
        }
    }
}

// ---------------------------------------------------------------------------
// Fused: BN+LeakyReLU + depthwise 3x3 (zero pad), single-Z input.
// ---------------------------------------------------------------------------
__global__ __launch_bounds__(256) void k_dw(
    const unsigned short* __restrict__ Zs,
    const float* __restrict__ psum,  // 128 x {sum,sumsq}
    const float* __restrict__ g,
    const float* __restrict__ b,
    const float* __restrict__ dwgt,  // 128 x 9
    ushort4* __restrict__ D)
{
    const int t  = blockIdx.x * 256 + threadIdx.x;  // 0..393215
    const int c  = t / 3072;
    const int gg = t - c * 3072;
    const int h  = gg / 48;
    const int w0 = (gg - h * 48) << 2;

    const float s   = psum[2 * c];
    const float q   = psum[2 * c + 1];
    const float mu  = s * (1.0f / HW);
    const float var = q * (1.0f / HW) - mu * mu;
    const float sc  = g[c] * rsqrtf(var + 1e-5f);
    const float sh  = b[c] - mu * sc;

    float wk[9];
    #pragma unroll
    for (int k = 0; k < 9; ++k) wk[k] = dwgt[c * 9 + k];

    const unsigned short* z0 = Zs + (size_t)c * HW;
    float v[3][6];
    #pragma unroll
    for (int ky = 0; ky < 3; ++ky) {
        const int hh  = h + ky - 1;
        const bool rin = (hh >= 0) && (hh < Himg);
        #pragma unroll
        for (int j = 0; j < 6; ++j) {
            const int ww = w0 - 1 + j;
            const bool in = rin && (ww >= 0) && (ww < Wimg);
            float z = in ? bf2f(z0[hh * Wimg + ww]) : 0.0f;
            float y = z * sc + sh;
            y = (y >= 0.0f) ? y : 0.01f * y;
            v[ky][j] = in ? y : 0.0f;
        }
    }

    ushort4 o;
    float oo[4];
    #pragma unroll
    for (int j = 0; j < 4; ++j) {
        float a = 0.0f;
        #pragma unroll
        for (int ky = 0; ky < 3; ++ky)
            #pragma unroll
            for (int kx = 0; kx < 3; ++kx)
                a += wk[ky * 3 + kx] * v[ky][j + kx];
        oo[j] = a;
    }
    o.x = f2bf(oo[0]); o.y = f2bf(oo[1]); o.z = f2bf(oo[2]); o.w = f2bf(oo[3]);
    D[t] = o;
}

// ---------------------------------------------------------------------------
// Final: BN+LeakyReLU, fp32 out, single-Z input.  grid = 1536.
// ---------------------------------------------------------------------------
__global__ __launch_bounds__(256) void k_final(
    const unsigned short* __restrict__ Zs,
    const float* __restrict__ psum,
    const float* __restrict__ g,
    const float* __restrict__ b,
    float4* __restrict__ out)
{
    const int f = blockIdx.x * 256 + threadIdx.x;
    const int c = f / 3072;

    const float s   = psum[2 * c];
    const float q   = psum[2 * c + 1];
    const float mu  = s * (1.0f / HW);
    const float var = q * (1.0f / HW) - mu * mu;
    const float sc  = g[c] * rsqrtf(var + 1e-5f);
    const float sh  = b[c] - mu * sc;

    uint2 a = ((const uint2*)Zs)[f];
    float4 v;
    v.x = bflo(a.x) * sc + sh; v.x = (v.x >= 0.0f) ? v.x : 0.01f * v.x;
    v.y = bfhi(a.x) * sc + sh; v.y = (v.y >= 0.0f) ? v.y : 0.01f * v.y;
    v.z = bflo(a.y) * sc + sh; v.z = (v.z >= 0.0f) ? v.z : 0.01f * v.z;
    v.w = bfhi(a.y) * sc + sh; v.w = (v.w >= 0.0f) ? v.w : 0.01f * v.w;
    out[f] = v;
}

// ---------------------------------------------------------------------------
extern "C" void kernel_launch(void* const* d_in, const int* in_sizes, int n_in,
                              void* d_out, int out_size, void* d_ws, size_t ws_size,
                              hipStream_t stream) {
    const float* x   = (const float*)d_in[0];
    const float* xr  = (const float*)d_in[1];
    const float* ro  = (const float*)d_in[2];
    const float* wr  = (const float*)d_in[3];
    const float* gr  = (const float*)d_in[4];
    const float* br  = (const float*)d_in[5];
    const float* dw1 = (const float*)d_in[6];
    const float* pw1 = (const float*)d_in[7];
    const float* g1  = (const float*)d_in[8];
    const float* b1  = (const float*)d_in[9];
    const float* dw2 = (const float*)d_in[10];
    const float* pw2 = (const float*)d_in[11];
    const float* g2  = (const float*)d_in[12];
    const float* b2  = (const float*)d_in[13];

    unsigned short* WS = (unsigned short*)d_ws;
    unsigned short* y0 = WS;                  // 256 x HW bf16
    unsigned short* Z1 = WS + 3145728;        // 128 x HW bf16
    unsigned short* D  = WS + 4718592;        // 128 x HW bf16 (dw out, reused)
    unsigned short* Z2 = WS + 6291456;
    unsigned short* Z3 = WS + 7864320;
    float* p1 = (float*)(WS + 9437184);       // 3 x 256 floats {sum,sumsq}
    float* p2 = p1 + 256;
    float* p3 = p2 + 256;
    unsigned short* W1h = WS + 9438720;       // 128x256 bf16 hi
    unsigned short* W1l = WS + 9471488;       // 128x256 bf16 lo
    unsigned short* W2h = WS + 9504256;       // 128x128
    unsigned short* W2l = WS + 9520640;
    unsigned short* W3h = WS + 9537024;
    unsigned short* W3l = WS + 9553408;
    float* out = (float*)d_out;

    k_wprep<<<256, 256, 0, stream>>>(wr, pw1, pw2, W1h, W1l, W2h, W2l, W3h, W3l, p1);
    k_deform<<<dim3(8, 192), 256, 0, stream>>>(x, xr, ro, y0);
    k_pw_mfma<256><<<dim3(384, 2), 256, 0, stream>>>(y0, W1h, W1l, Z1, p1);
    k_dw<<<1536, 256, 0, stream>>>(Z1, p1, gr, br, dw1, (ushort4*)D);
    k_pw_mfma<128><<<dim3(384, 2), 256, 0, stream>>>(D, W2h, W2l, Z2, p2);
    k_dw<<<1536, 256, 0, stream>>>(Z2, p2, g1, b1, dw2, (ushort4*)D);
    k_pw_mfma<128><<<dim3(384, 2), 256, 0, stream>>>(D, W3h, W3l, Z3, p3);
    k_final<<<1536, 256, 0, stream>>>(Z3, p3, g2, b2, (float4*)out);
}

// Round 3
// 193.419 us; speedup vs baseline: 2.1513x; 2.0730x over previous
//
#include <hip/hip_runtime.h>

#define HW    12288
#define Wimg  192
#define Himg  64
#define Wpad  194
#define Ppad  12804   // 66*194

typedef __attribute__((ext_vector_type(8))) __bf16 bf16x8;
typedef __attribute__((ext_vector_type(4))) float  f32x4;

// bf16 <-> fp32 helpers (RNE), header-independent
static __device__ __forceinline__ unsigned short f2bf(float f) {
    union { float f; unsigned int u; } v; v.f = f;
    unsigned int r = v.u + 0x7fffu + ((v.u >> 16) & 1u);
    return (unsigned short)(r >> 16);
}
static __device__ __forceinline__ float bf2f(unsigned short h) {
    union { unsigned int u; float f; } v; v.u = ((unsigned int)h) << 16;
    return v.f;
}
static __device__ __forceinline__ float bflo(unsigned int u) {
    union { unsigned int u; float f; } v; v.u = u << 16; return v.f;
}
static __device__ __forceinline__ float bfhi(unsigned int u) {
    union { unsigned int u; float f; } v; v.u = u & 0xffff0000u; return v.f;
}

// ---------------------------------------------------------------------------
// R23: weight prep — fp32 W -> bf16 hi/lo pair (fp32-equivalent precision in
// the 2-MFMA scheme).  Runs once, ~65k elements.
// ---------------------------------------------------------------------------
__global__ __launch_bounds__(256) void k_wprep(
    const float* __restrict__ wr,    // 128 x 256
    const float* __restrict__ pw1,   // 128 x 128
    const float* __restrict__ pw2,   // 128 x 128
    unsigned short* __restrict__ W1h, unsigned short* __restrict__ W1l,
    unsigned short* __restrict__ W2h, unsigned short* __restrict__ W2l,
    unsigned short* __restrict__ W3h, unsigned short* __restrict__ W3l)
{
    const int idx = blockIdx.x * 256 + threadIdx.x;
    float v;
    unsigned short *dh, *dl;
    if (idx < 32768)      { v = wr[idx];          dh = W1h + idx; dl = W1l + idx; }
    else if (idx < 49152) { int t = idx - 32768;  v = pw1[t]; dh = W2h + t; dl = W2l + t; }
    else                  { int t = idx - 49152;  v = pw2[t]; dh = W3h + t; dl = W3l + t; }
    unsigned short h = f2bf(v);
    *dh = h;
    *dl = f2bf(v - bf2f(h));
}

// ---------------------------------------------------------------------------
// K1: deformable gather via LDS-staged windows (flat-space staging).
// Unchanged math (R15-R19 proven).
// ---------------------------------------------------------------------------
__global__ __launch_bounds__(256, 6) void k_deform(
    const float* __restrict__ x,     // 256 x HW
    const float* __restrict__ xr,    // HW
    const float* __restrict__ rout,  // 256 x 9
    unsigned short* __restrict__ y0) // 256 x HW (bf16)
{
    __shared__ unsigned short s_x[32][240];  // 3 window rows x stride 80

    const int cblk = blockIdx.x;     // 0..7   (fastest -> XCD id)
    const int tile = blockIdx.y;     // 0..191
    const int tid  = threadIdx.x;
    const int pl   = tid & 63;
    const int wv   = __builtin_amdgcn_readfirstlane(tid >> 6);
    const int h    = tile / 3;
    const int w0   = (tile - h * 3) * 64;
    const int w    = w0 + pl;
    const int gp   = h * Wimg + w;

    int   li[6];
    float gw[6][3];
    const float off = 3.0f / (1.0f + expf(-xr[gp]));

    #pragma unroll
    for (int t = 0; t < 6; ++t) {
        const int xo = (t & 1) ? 1 : -1;
        const int yo = (t >> 1) - 1;
        float ov  = off * (float)xo;
        int   iv  = yo * Wpad;
        int   pre = (h + 1) * Wpad + (w + 1) + xo + iv;
        float after = (float)(pre + iv) + ov;
        int fl = (int)floorf(ov);
        int ce = (int)ceilf(ov);
        int av_f  = min(max(pre + fl + iv, 0), Ppad - 1);
        int av_f1 = min(max(av_f + xo,    0), Ppad - 1);
        int av_c  = min(max(pre + ce + iv, 0), Ppad - 1);
        int av_c1 = min(max(av_c + xo,    0), Ppad - 1);
        float wf  = fabsf(after - (float)av_f);
        float wf1 = fabsf((float)av_f1 - after);
        float wc1 = fabsf(after - (float)av_c1);
        float wc  = fabsf((float)av_c - after);
        float s1 = wf  * (1.0f / Wpad);
        float s2 = wc1 * (1.0f / Wpad);
        int   i4[4] = { av_f, av_f1, av_c1, av_c };
        float w4[4] = { s1 * wf, s1 * wf1, s2 * wc1, s2 * wc };
        int b = min(min(i4[0], i4[1]), min(i4[2], i4[3]));
        const int base = (h + 1 + 2 * yo) * Wpad + w0 - 4;
        li[t] = (t >> 1) * 80 + min(max(b - base, 0), 71);
        #pragma unroll
        for (int s = 0; s < 3; ++s) {
            float ws = 0.0f;
            #pragma unroll
            for (int j = 0; j < 4; ++j)
                ws += (i4[j] == b + s) ? w4[j] : 0.0f;
            int av = b + s;
            int r  = av / Wpad;
            int cc = av - r * Wpad;
            bool inb = (r >= 1) && (r <= Himg) && (cc >= 1) && (cc <= Wimg);
            gw[t][s] = inb ? ws : 0.0f;
        }
    }

    // stage the 3x74 flat windows for the block's 32 channels (bf16)
    const int jj = tid;
    int  xoff = 0;
    bool valid = false;
    int  rr = 0, jcol = 0;
    if (jj < 222) {
        rr   = jj / 74;
        jcol = jj - rr * 74;
        const int flat = (h + 1 + 2 * (rr - 1)) * Wpad + w0 - 4 + jcol;
        if (flat >= 0 && flat < Ppad) {
            const int r = flat / Wpad;
            const int c = flat - r * Wpad;
            valid = (r >= 1) && (r <= Himg) && (c >= 1) && (c <= Wimg);
            xoff  = valid ? ((r - 1) * Wimg + (c - 1)) : 0;
        }
    }
    const float* xb = x + (size_t)(cblk * 32) * HW;
    for (int c = 0; c < 32; ++c) {
        if (jj < 222) {
            float v = valid ? xb[(size_t)c * HW + xoff] : 0.0f;
            s_x[c][rr * 80 + jcol] = f2bf(v);
        }
    }
    __syncthreads();

    const int c0l = wv * 8;
    #pragma unroll 2
    for (int i = 0; i < 8; ++i) {
        const int cl = c0l + i;
        const unsigned short* sxc = s_x[cl];
        const float* rc = rout + (cblk * 32 + cl) * 9;
        float acc = 0.0f;
        #pragma unroll
        for (int t = 0; t < 6; ++t) {
            float part = gw[t][0] * bf2f(sxc[li[t]])
                       + gw[t][1] * bf2f(sxc[li[t] + 1])
                       + gw[t][2] * bf2f(sxc[li[t] + 2]);
            const int k = 3 * (t >> 1) + ((t & 1) ? 2 : 0);
            acc += rc[k] * part;
        }
        y0[(size_t)(cblk * 32 + cl) * HW + gp] = f2bf(acc);
    }
}

// ---------------------------------------------------------------------------
// R23: MFMA pointwise GEMM.  Same math as R21/R22, but the fused BN-stats
// epilogue writes NON-ATOMIC per-block partials (atomicAdd drain was the
// 85us pathology: ~98k RMWs onto 16 cache lines serialize at the coherence
// point).  part[bx][2*ch+st]; k_red folds 384 partials -> psum.
// Block: 4 waves x (16 o x 32 px).  Grid (384 px-blocks, 2 o-blocks) = 768.
// ---------------------------------------------------------------------------
template <int CIN>
__global__ __launch_bounds__(256, 4) void k_pw_mfma(
    const unsigned short* __restrict__ Aact,  // CIN x HW (bf16)
    const unsigned short* __restrict__ Whi,   // 128 x CIN (bf16)
    const unsigned short* __restrict__ Wlo,   // 128 x CIN (bf16)
    unsigned short* __restrict__ Z,           // 128 x HW (bf16)
    float* __restrict__ part)                 // 384 x 256 {sum,sumsq} partials
{
    constexpr int KC = CIN / 32;
    constexpr int RS = CIN + 8;               // pad keeps b128 16B-aligned
    __shared__ __align__(16) unsigned short s_b[32][RS];

    const int tid = threadIdx.x;
    const int l   = tid & 63;
    const int wv  = tid >> 6;
    const int px0 = blockIdx.x * 32;
    const int o0  = blockIdx.y * 64;

    // ---- stage act tile transposed: s_b[p][c ^ (((p>>4)&3)<<3)] ----
    {
        const int cs  = tid >> 1;             // 0..127
        const int pxb = (tid & 1) << 4;       // 0 or 16
        const int swz = (tid & 1) << 3;       // (p>>4)&3 == tid&1 here
        #pragma unroll
        for (int it = 0; it < CIN / 128; ++it) {
            const int c = cs + it * 128;
            const uint4* src = (const uint4*)(Aact + (size_t)c * HW + px0 + pxb);
            uint4 u0 = src[0];
            uint4 u1 = src[1];
            const int sc = c ^ swz;
            unsigned int wd[8] = {u0.x, u0.y, u0.z, u0.w, u1.x, u1.y, u1.z, u1.w};
            #pragma unroll
            for (int e = 0; e < 8; ++e) {
                s_b[pxb + 2 * e    ][sc] = (unsigned short)(wd[e] & 0xffffu);
                s_b[pxb + 2 * e + 1][sc] = (unsigned short)(wd[e] >> 16);
            }
        }
    }

    // weight fragment base: row m = l&15, k-group = l>>4 (8 consecutive c)
    const int orow = o0 + wv * 16 + (l & 15);
    const unsigned short* whp = Whi + (size_t)orow * CIN + ((l >> 4) << 3);
    const unsigned short* wlp = Wlo + (size_t)orow * CIN + ((l >> 4) << 3);

    __syncthreads();

    // ---- MFMA K-loop: per kc = 2 weight b128 loads + 2 LDS b128 + 4 MFMA ----
    f32x4 acc[2] = { {0.f, 0.f, 0.f, 0.f}, {0.f, 0.f, 0.f, 0.f} };
    const int prow = l & 15;
    const int kg8  = l >> 4;
    #pragma unroll 4
    for (int kc = 0; kc < KC; ++kc) {
        bf16x8 wh = *(const bf16x8*)(whp + kc * 32);
        bf16x8 wl = *(const bf16x8*)(wlp + kc * 32);
        #pragma unroll
        for (int ip = 0; ip < 2; ++ip) {
            const int col = kc * 32 + (((kg8 ^ ip) & 3) << 3);
            bf16x8 bfr = *(const bf16x8*)&s_b[ip * 16 + prow][col];
            acc[ip] = __builtin_amdgcn_mfma_f32_16x16x32_bf16(wh, bfr, acc[ip], 0, 0, 0);
            acc[ip] = __builtin_amdgcn_mfma_f32_16x16x32_bf16(wl, bfr, acc[ip], 0, 0, 0);
        }
    }

    // ---- epilogue: store Z (bf16) + per-block partial BN stats (no atomics) ----
    // D layout: col = l&15 (px), row m = (l>>4)*4 + r  (m89-verified)
    float* pp = part + (size_t)blockIdx.x * 256;
    const int obase = o0 + wv * 16 + ((l >> 4) << 2);
    #pragma unroll
    for (int r = 0; r < 4; ++r) {
        const int ch = obase + r;
        float v0 = acc[0][r];
        float v1 = acc[1][r];
        Z[(size_t)ch * HW + px0 + prow]      = f2bf(v0);
        Z[(size_t)ch * HW + px0 + 16 + prow] = f2bf(v1);
        float s = v0 + v1;
        float q = v0 * v0 + v1 * v1;
        s += __shfl_xor(s, 1, 64);  q += __shfl_xor(q, 1, 64);
        s += __shfl_xor(s, 2, 64);  q += __shfl_xor(q, 2, 64);
        s += __shfl_xor(s, 4, 64);  q += __shfl_xor(q, 4, 64);
        s += __shfl_xor(s, 8, 64);  q += __shfl_xor(q, 8, 64);
        if (prow == 0) {
            pp[2 * ch]     = s;
            pp[2 * ch + 1] = q;
        }
    }
}

// ---------------------------------------------------------------------------
// R23: fold 384 per-block stat partials -> psum[256].  One block, 256 thr.
// ---------------------------------------------------------------------------
__global__ __launch_bounds__(256) void k_red(
    const float* __restrict__ part,  // 384 x 256
    float* __restrict__ psum)        // 256
{
    const int t = threadIdx.x;
    float s = 0.0f;
    #pragma unroll 8
    for (int b = 0; b < 384; ++b) s += part[b * 256 + t];
    psum[t] = s;
}

// ---------------------------------------------------------------------------
// Fused: BN+LeakyReLU + depthwise 3x3 (zero pad), single-Z input.
// ---------------------------------------------------------------------------
__global__ __launch_bounds__(256) void k_dw(
    const unsigned short* __restrict__ Zs,
    const float* __restrict__ psum,  // 128 x {sum,sumsq}
    const float* __restrict__ g,
    const float* __restrict__ b,
    const float* __restrict__ dwgt,  // 128 x 9
    ushort4* __restrict__ D)
{
    const int t  = blockIdx.x * 256 + threadIdx.x;  // 0..393215
    const int c  = t / 3072;
    const int gg = t - c * 3072;
    const int h  = gg / 48;
    const int w0 = (gg - h * 48) << 2;

    const float s   = psum[2 * c];
    const float q   = psum[2 * c + 1];
    const float mu  = s * (1.0f / HW);
    const float var = q * (1.0f / HW) - mu * mu;
    const float sc  = g[c] * rsqrtf(var + 1e-5f);
    const float sh  = b[c] - mu * sc;

    float wk[9];
    #pragma unroll
    for (int k = 0; k < 9; ++k) wk[k] = dwgt[c * 9 + k];

    const unsigned short* z0 = Zs + (size_t)c * HW;
    float v[3][6];
    #pragma unroll
    for (int ky = 0; ky < 3; ++ky) {
        const int hh  = h + ky - 1;
        const bool rin = (hh >= 0) && (hh < Himg);
        #pragma unroll
        for (int j = 0; j < 6; ++j) {
            const int ww = w0 - 1 + j;
            const bool in = rin && (ww >= 0) && (ww < Wimg);
            float z = in ? bf2f(z0[hh * Wimg + ww]) : 0.0f;
            float y = z * sc + sh;
            y = (y >= 0.0f) ? y : 0.01f * y;
            v[ky][j] = in ? y : 0.0f;
        }
    }

    ushort4 o;
    float oo[4];
    #pragma unroll
    for (int j = 0; j < 4; ++j) {
        float a = 0.0f;
        #pragma unroll
        for (int ky = 0; ky < 3; ++ky)
            #pragma unroll
            for (int kx = 0; kx < 3; ++kx)
                a += wk[ky * 3 + kx] * v[ky][j + kx];
        oo[j] = a;
    }
    o.x = f2bf(oo[0]); o.y = f2bf(oo[1]); o.z = f2bf(oo[2]); o.w = f2bf(oo[3]);
    D[t] = o;
}

// ---------------------------------------------------------------------------
// Final: BN+LeakyReLU, fp32 out, single-Z input.  grid = 1536.
// ---------------------------------------------------------------------------
__global__ __launch_bounds__(256) void k_final(
    const unsigned short* __restrict__ Zs,
    const float* __restrict__ psum,
    const float* __restrict__ g,
    const float* __restrict__ b,
    float4* __restrict__ out)
{
    const int f = blockIdx.x * 256 + threadIdx.x;
    const int c = f / 3072;

    const float s   = psum[2 * c];
    const float q   = psum[2 * c + 1];
    const float mu  = s * (1.0f / HW);
    const float var = q * (1.0f / HW) - mu * mu;
    const float sc  = g[c] * rsqrtf(var + 1e-5f);
    const float sh  = b[c] - mu * sc;

    uint2 a = ((const uint2*)Zs)[f];
    float4 v;
    v.x = bflo(a.x) * sc + sh; v.x = (v.x >= 0.0f) ? v.x : 0.01f * v.x;
    v.y = bfhi(a.x) * sc + sh; v.y = (v.y >= 0.0f) ? v.y : 0.01f * v.y;
    v.z = bflo(a.y) * sc + sh; v.z = (v.z >= 0.0f) ? v.z : 0.01f * v.z;
    v.w = bfhi(a.y) * sc + sh; v.w = (v.w >= 0.0f) ? v.w : 0.01f * v.w;
    out[f] = v;
}

// ---------------------------------------------------------------------------
extern "C" void kernel_launch(void* const* d_in, const int* in_sizes, int n_in,
                              void* d_out, int out_size, void* d_ws, size_t ws_size,
                              hipStream_t stream) {
    const float* x   = (const float*)d_in[0];
    const float* xr  = (const float*)d_in[1];
    const float* ro  = (const float*)d_in[2];
    const float* wr  = (const float*)d_in[3];
    const float* gr  = (const float*)d_in[4];
    const float* br  = (const float*)d_in[5];
    const float* dw1 = (const float*)d_in[6];
    const float* pw1 = (const float*)d_in[7];
    const float* g1  = (const float*)d_in[8];
    const float* b1  = (const float*)d_in[9];
    const float* dw2 = (const float*)d_in[10];
    const float* pw2 = (const float*)d_in[11];
    const float* g2  = (const float*)d_in[12];
    const float* b2  = (const float*)d_in[13];

    unsigned short* WS = (unsigned short*)d_ws;
    unsigned short* y0 = WS;                  // 256 x HW bf16
    unsigned short* Z1 = WS + 3145728;        // 128 x HW bf16
    unsigned short* D  = WS + 4718592;        // 128 x HW bf16 (dw out, reused)
    unsigned short* Z2 = WS + 6291456;
    unsigned short* Z3 = WS + 7864320;
    float* p1 = (float*)(WS + 9437184);       // 3 x 256 floats {sum,sumsq}
    float* p2 = p1 + 256;
    float* p3 = p2 + 256;
    unsigned short* W1h = WS + 9438720;       // 128x256 bf16 hi
    unsigned short* W1l = WS + 9471488;       // 128x256 bf16 lo
    unsigned short* W2h = WS + 9504256;       // 128x128
    unsigned short* W2l = WS + 9520640;
    unsigned short* W3h = WS + 9537024;
    unsigned short* W3l = WS + 9553408;
    // stat partials (384 x 256 fp32 = 384 KB) live in dead Z-slots:
    float* part1 = (float*)(WS + 6291456);    // Z2 slot (written later by pw2)
    float* part2 = (float*)WS;                // y0 slot (dead after pw1)
    float* part3 = (float*)WS;                // y0 slot (still dead)
    float* out = (float*)d_out;

    k_wprep<<<256, 256, 0, stream>>>(wr, pw1, pw2, W1h, W1l, W2h, W2l, W3h, W3l);
    k_deform<<<dim3(8, 192), 256, 0, stream>>>(x, xr, ro, y0);
    k_pw_mfma<256><<<dim3(384, 2), 256, 0, stream>>>(y0, W1h, W1l, Z1, part1);
    k_red<<<1, 256, 0, stream>>>(part1, p1);
    k_dw<<<1536, 256, 0, stream>>>(Z1, p1, gr, br, dw1, (ushort4*)D);
    k_pw_mfma<128><<<dim3(384, 2), 256, 0, stream>>>(D, W2h, W2l, Z2, part2);
    k_red<<<1, 256, 0, stream>>>(part2, p2);
    k_dw<<<1536, 256, 0, stream>>>(Z2, p2, g1, b1, dw2, (ushort4*)D);
    k_pw_mfma<128><<<dim3(384, 2), 256, 0, stream>>>(D, W3h, W3l, Z3, part3);
    k_red<<<1, 256, 0, stream>>>(part3, p3);
    k_final<<<1536, 256, 0, stream>>>(Z3, p3, g2, b2, (float4*)out);
}

// Round 4
// 152.538 us; speedup vs baseline: 2.7278x; 1.2680x over previous
//
#include <hip/hip_runtime.h>

#define HW    12288
#define Wimg  192
#define Himg  64
#define Wpad  194
#define Ppad  12804   // 66*194

typedef __attribute__((ext_vector_type(8))) __bf16 bf16x8;
typedef __attribute__((ext_vector_type(4))) float  f32x4;

// bf16 <-> fp32 helpers (RNE), header-independent
static __device__ __forceinline__ unsigned short f2bf(float f) {
    union { float f; unsigned int u; } v; v.f = f;
    unsigned int r = v.u + 0x7fffu + ((v.u >> 16) & 1u);
    return (unsigned short)(r >> 16);
}
static __device__ __forceinline__ float bf2f(unsigned short h) {
    union { unsigned int u; float f; } v; v.u = ((unsigned int)h) << 16;
    return v.f;
}
static __device__ __forceinline__ float bflo(unsigned int u) {
    union { unsigned int u; float f; } v; v.u = u << 16; return v.f;
}
static __device__ __forceinline__ float bfhi(unsigned int u) {
    union { unsigned int u; float f; } v; v.u = u & 0xffff0000u; return v.f;
}

// ---------------------------------------------------------------------------
// K1: deformable gather via LDS-staged windows (flat-space staging).
// Unchanged math (R15-R19 proven).  R24: blockIdx.y==192 stripe does the
// weight prep (fp32 -> bf16 hi/lo split) that was k_wprep.
// ---------------------------------------------------------------------------
__global__ __launch_bounds__(256, 6) void k_deform(
    const float* __restrict__ x,     // 256 x HW
    const float* __restrict__ xr,    // HW
    const float* __restrict__ rout,  // 256 x 9
    unsigned short* __restrict__ y0, // 256 x HW (bf16)
    const float* __restrict__ wr,    // 128 x 256
    const float* __restrict__ pw1,   // 128 x 128
    const float* __restrict__ pw2,   // 128 x 128
    unsigned short* __restrict__ W1h, unsigned short* __restrict__ W1l,
    unsigned short* __restrict__ W2h, unsigned short* __restrict__ W2l,
    unsigned short* __restrict__ W3h, unsigned short* __restrict__ W3l)
{
    __shared__ unsigned short s_x[32][240];  // 3 window rows x stride 80

    const int cblk = blockIdx.x;     // 0..7   (fastest -> XCD id)
    const int tile = blockIdx.y;     // 0..191 deform, 192 = weight prep
    const int tid  = threadIdx.x;

    if (tile == 192) {
        const int base = cblk * 256 + tid;   // 0..2047
        #pragma unroll
        for (int k = 0; k < 32; ++k) {
            const int idx = base + k * 2048;
            float v;
            unsigned short *dh, *dl;
            if (idx < 32768)      { v = wr[idx];         dh = W1h + idx; dl = W1l + idx; }
            else if (idx < 49152) { int u = idx - 32768; v = pw1[u]; dh = W2h + u; dl = W2l + u; }
            else                  { int u = idx - 49152; v = pw2[u]; dh = W3h + u; dl = W3l + u; }
            unsigned short hh = f2bf(v);
            *dh = hh;
            *dl = f2bf(v - bf2f(hh));
        }
        return;
    }

    const int pl   = tid & 63;
    const int wv   = __builtin_amdgcn_readfirstlane(tid >> 6);
    const int h    = tile / 3;
    const int w0   = (tile - h * 3) * 64;
    const int w    = w0 + pl;
    const int gp   = h * Wimg + w;

    int   li[6];
    float gw[6][3];
    const float off = 3.0f / (1.0f + expf(-xr[gp]));

    #pragma unroll
    for (int t = 0; t < 6; ++t) {
        const int xo = (t & 1) ? 1 : -1;
        const int yo = (t >> 1) - 1;
        float ov  = off * (float)xo;
        int   iv  = yo * Wpad;
        int   pre = (h + 1) * Wpad + (w + 1) + xo + iv;
        float after = (float)(pre + iv) + ov;
        int fl = (int)floorf(ov);
        int ce = (int)ceilf(ov);
        int av_f  = min(max(pre + fl + iv, 0), Ppad - 1);
        int av_f1 = min(max(av_f + xo,    0), Ppad - 1);
        int av_c  = min(max(pre + ce + iv, 0), Ppad - 1);
        int av_c1 = min(max(av_c + xo,    0), Ppad - 1);
        float wf  = fabsf(after - (float)av_f);
        float wf1 = fabsf((float)av_f1 - after);
        float wc1 = fabsf(after - (float)av_c1);
        float wc  = fabsf((float)av_c - after);
        float s1 = wf  * (1.0f / Wpad);
        float s2 = wc1 * (1.0f / Wpad);
        int   i4[4] = { av_f, av_f1, av_c1, av_c };
        float w4[4] = { s1 * wf, s1 * wf1, s2 * wc1, s2 * wc };
        int b = min(min(i4[0], i4[1]), min(i4[2], i4[3]));
        const int base = (h + 1 + 2 * yo) * Wpad + w0 - 4;
        li[t] = (t >> 1) * 80 + min(max(b - base, 0), 71);
        #pragma unroll
        for (int s = 0; s < 3; ++s) {
            float ws = 0.0f;
            #pragma unroll
            for (int j = 0; j < 4; ++j)
                ws += (i4[j] == b + s) ? w4[j] : 0.0f;
            int av = b + s;
            int r  = av / Wpad;
            int cc = av - r * Wpad;
            bool inb = (r >= 1) && (r <= Himg) && (cc >= 1) && (cc <= Wimg);
            gw[t][s] = inb ? ws : 0.0f;
        }
    }

    // stage the 3x74 flat windows for the block's 32 channels (bf16)
    const int jj = tid;
    int  xoff = 0;
    bool valid = false;
    int  rr = 0, jcol = 0;
    if (jj < 222) {
        rr   = jj / 74;
        jcol = jj - rr * 74;
        const int flat = (h + 1 + 2 * (rr - 1)) * Wpad + w0 - 4 + jcol;
        if (flat >= 0 && flat < Ppad) {
            const int r = flat / Wpad;
            const int c = flat - r * Wpad;
            valid = (r >= 1) && (r <= Himg) && (c >= 1) && (c <= Wimg);
            xoff  = valid ? ((r - 1) * Wimg + (c - 1)) : 0;
        }
    }
    const float* xb = x + (size_t)(cblk * 32) * HW;
    for (int c = 0; c < 32; ++c) {
        if (jj < 222) {
            float v = valid ? xb[(size_t)c * HW + xoff] : 0.0f;
            s_x[c][rr * 80 + jcol] = f2bf(v);
        }
    }
    __syncthreads();

    const int c0l = wv * 8;
    #pragma unroll 2
    for (int i = 0; i < 8; ++i) {
        const int cl = c0l + i;
        const unsigned short* sxc = s_x[cl];
        const float* rc = rout + (cblk * 32 + cl) * 9;
        float acc = 0.0f;
        #pragma unroll
        for (int t = 0; t < 6; ++t) {
            float part = gw[t][0] * bf2f(sxc[li[t]])
                       + gw[t][1] * bf2f(sxc[li[t] + 1])
                       + gw[t][2] * bf2f(sxc[li[t] + 2]);
            const int k = 3 * (t >> 1) + ((t & 1) ? 2 : 0);
            acc += rc[k] * part;
        }
        y0[(size_t)(cblk * 32 + cl) * HW + gp] = f2bf(acc);
    }
}

// ---------------------------------------------------------------------------
// R23: MFMA pointwise GEMM.  Fused BN-stats epilogue writes NON-ATOMIC
// per-block partials; consumers fold them.
// Block: 4 waves x (16 o x 32 px).  Grid (384 px-blocks, 2 o-blocks) = 768.
// ---------------------------------------------------------------------------
template <int CIN>
__global__ __launch_bounds__(256, 4) void k_pw_mfma(
    const unsigned short* __restrict__ Aact,  // CIN x HW (bf16)
    const unsigned short* __restrict__ Whi,   // 128 x CIN (bf16)
    const unsigned short* __restrict__ Wlo,   // 128 x CIN (bf16)
    unsigned short* __restrict__ Z,           // 128 x HW (bf16)
    float* __restrict__ part)                 // 384 x 256 {sum,sumsq} partials
{
    constexpr int KC = CIN / 32;
    constexpr int RS = CIN + 8;               // pad keeps b128 16B-aligned
    __shared__ __align__(16) unsigned short s_b[32][RS];

    const int tid = threadIdx.x;
    const int l   = tid & 63;
    const int wv  = tid >> 6;
    const int px0 = blockIdx.x * 32;
    const int o0  = blockIdx.y * 64;

    // ---- stage act tile transposed: s_b[p][c ^ (((p>>4)&3)<<3)] ----
    {
        const int cs  = tid >> 1;             // 0..127
        const int pxb = (tid & 1) << 4;       // 0 or 16
        const int swz = (tid & 1) << 3;       // (p>>4)&3 == tid&1 here
        #pragma unroll
        for (int it = 0; it < CIN / 128; ++it) {
            const int c = cs + it * 128;
            const uint4* src = (const uint4*)(Aact + (size_t)c * HW + px0 + pxb);
            uint4 u0 = src[0];
            uint4 u1 = src[1];
            const int sc = c ^ swz;
            unsigned int wd[8] = {u0.x, u0.y, u0.z, u0.w, u1.x, u1.y, u1.z, u1.w};
            #pragma unroll
            for (int e = 0; e < 8; ++e) {
                s_b[pxb + 2 * e    ][sc] = (unsigned short)(wd[e] & 0xffffu);
                s_b[pxb + 2 * e + 1][sc] = (unsigned short)(wd[e] >> 16);
            }
        }
    }

    // weight fragment base: row m = l&15, k-group = l>>4 (8 consecutive c)
    const int orow = o0 + wv * 16 + (l & 15);
    const unsigned short* whp = Whi + (size_t)orow * CIN + ((l >> 4) << 3);
    const unsigned short* wlp = Wlo + (size_t)orow * CIN + ((l >> 4) << 3);

    __syncthreads();

    // ---- MFMA K-loop: per kc = 2 weight b128 loads + 2 LDS b128 + 4 MFMA ----
    f32x4 acc[2] = { {0.f, 0.f, 0.f, 0.f}, {0.f, 0.f, 0.f, 0.f} };
    const int prow = l & 15;
    const int kg8  = l >> 4;
    #pragma unroll 4
    for (int kc = 0; kc < KC; ++kc) {
        bf16x8 wh = *(const bf16x8*)(whp + kc * 32);
        bf16x8 wl = *(const bf16x8*)(wlp + kc * 32);
        #pragma unroll
        for (int ip = 0; ip < 2; ++ip) {
            const int col = kc * 32 + (((kg8 ^ ip) & 3) << 3);
            bf16x8 bfr = *(const bf16x8*)&s_b[ip * 16 + prow][col];
            acc[ip] = __builtin_amdgcn_mfma_f32_16x16x32_bf16(wh, bfr, acc[ip], 0, 0, 0);
            acc[ip] = __builtin_amdgcn_mfma_f32_16x16x32_bf16(wl, bfr, acc[ip], 0, 0, 0);
        }
    }

    // ---- epilogue: store Z (bf16) + per-block partial BN stats (no atomics) ----
    // D layout: col = l&15 (px), row m = (l>>4)*4 + r  (m89-verified)
    float* pp = part + (size_t)blockIdx.x * 256;
    const int obase = o0 + wv * 16 + ((l >> 4) << 2);
    #pragma unroll
    for (int r = 0; r < 4; ++r) {
        const int ch = obase + r;
        float v0 = acc[0][r];
        float v1 = acc[1][r];
        Z[(size_t)ch * HW + px0 + prow]      = f2bf(v0);
        Z[(size_t)ch * HW + px0 + 16 + prow] = f2bf(v1);
        float s = v0 + v1;
        float q = v0 * v0 + v1 * v1;
        s += __shfl_xor(s, 1, 64);  q += __shfl_xor(q, 1, 64);
        s += __shfl_xor(s, 2, 64);  q += __shfl_xor(q, 2, 64);
        s += __shfl_xor(s, 4, 64);  q += __shfl_xor(q, 4, 64);
        s += __shfl_xor(s, 8, 64);  q += __shfl_xor(q, 8, 64);
        if (prow == 0) {
            pp[2 * ch]     = s;
            pp[2 * ch + 1] = q;
        }
    }
}

// ---------------------------------------------------------------------------
// R24: fused stats-fold + BN+LeakyReLU + depthwise 3x3 (zero pad).
// Each block covers exactly one channel (3072 px / 256 thr = 12 blocks/ch),
// so it folds that channel's 384 partials itself (L2-hot, ~2 loads/thread).
// ---------------------------------------------------------------------------
__global__ __launch_bounds__(256) void k_dw(
    const unsigned short* __restrict__ Zs,
    const float* __restrict__ part,  // 384 x 256 partials
    const float* __restrict__ g,
    const float* __restrict__ b,
    const float* __restrict__ dwgt,  // 128 x 9
    ushort4* __restrict__ D)
{
    __shared__ float rs[4], rq[4];
    const int tid = threadIdx.x;
    const int c   = blockIdx.x / 12;          // 12 blocks per channel

    // fold this channel's partials
    float s = 0.0f, q = 0.0f;
    for (int bb = tid; bb < 384; bb += 256) {
        const float* pb = part + (size_t)bb * 256 + 2 * c;
        s += pb[0];
        q += pb[1];
    }
    #pragma unroll
    for (int off = 32; off > 0; off >>= 1) {
        s += __shfl_down(s, off, 64);
        q += __shfl_down(q, off, 64);
    }
    if ((tid & 63) == 0) { rs[tid >> 6] = s; rq[tid >> 6] = q; }
    __syncthreads();
    s = rs[0] + rs[1] + rs[2] + rs[3];
    q = rq[0] + rq[1] + rq[2] + rq[3];

    const int t  = blockIdx.x * 256 + tid;    // 0..393215
    const int gg = t - c * 3072;
    const int h  = gg / 48;
    const int w0 = (gg - h * 48) << 2;

    const float mu  = s * (1.0f / HW);
    const float var = q * (1.0f / HW) - mu * mu;
    const float sc  = g[c] * rsqrtf(var + 1e-5f);
    const float sh  = b[c] - mu * sc;

    float wk[9];
    #pragma unroll
    for (int k = 0; k < 9; ++k) wk[k] = dwgt[c * 9 + k];

    const unsigned short* z0 = Zs + (size_t)c * HW;
    float v[3][6];
    #pragma unroll
    for (int ky = 0; ky < 3; ++ky) {
        const int hh  = h + ky - 1;
        const bool rin = (hh >= 0) && (hh < Himg);
        #pragma unroll
        for (int j = 0; j < 6; ++j) {
            const int ww = w0 - 1 + j;
            const bool in = rin && (ww >= 0) && (ww < Wimg);
            float z = in ? bf2f(z0[hh * Wimg + ww]) : 0.0f;
            float y = z * sc + sh;
            y = (y >= 0.0f) ? y : 0.01f * y;
            v[ky][j] = in ? y : 0.0f;
        }
    }

    ushort4 o;
    float oo[4];
    #pragma unroll
    for (int j = 0; j < 4; ++j) {
        float a = 0.0f;
        #pragma unroll
        for (int ky = 0; ky < 3; ++ky)
            #pragma unroll
            for (int kx = 0; kx < 3; ++kx)
                a += wk[ky * 3 + kx] * v[ky][j + kx];
        oo[j] = a;
    }
    o.x = f2bf(oo[0]); o.y = f2bf(oo[1]); o.z = f2bf(oo[2]); o.w = f2bf(oo[3]);
    D[t] = o;
}

// ---------------------------------------------------------------------------
// R24: fused stats-fold + BN+LeakyReLU, fp32 out.  grid = 1536.
// ---------------------------------------------------------------------------
__global__ __launch_bounds__(256) void k_final(
    const unsigned short* __restrict__ Zs,
    const float* __restrict__ part,  // 384 x 256 partials
    const float* __restrict__ g,
    const float* __restrict__ b,
    float4* __restrict__ out)
{
    __shared__ float rs[4], rq[4];
    const int tid = threadIdx.x;
    const int c   = blockIdx.x / 12;          // 12 blocks per channel

    float s = 0.0f, q = 0.0f;
    for (int bb = tid; bb < 384; bb += 256) {
        const float* pb = part + (size_t)bb * 256 + 2 * c;
        s += pb[0];
        q += pb[1];
    }
    #pragma unroll
    for (int off = 32; off > 0; off >>= 1) {
        s += __shfl_down(s, off, 64);
        q += __shfl_down(q, off, 64);
    }
    if ((tid & 63) == 0) { rs[tid >> 6] = s; rq[tid >> 6] = q; }
    __syncthreads();
    s = rs[0] + rs[1] + rs[2] + rs[3];
    q = rq[0] + rq[1] + rq[2] + rq[3];

    const float mu  = s * (1.0f / HW);
    const float var = q * (1.0f / HW) - mu * mu;
    const float sc  = g[c] * rsqrtf(var + 1e-5f);
    const float sh  = b[c] - mu * sc;

    const int f = blockIdx.x * 256 + tid;
    uint2 a = ((const uint2*)Zs)[f];
    float4 v;
    v.x = bflo(a.x) * sc + sh; v.x = (v.x >= 0.0f) ? v.x : 0.01f * v.x;
    v.y = bfhi(a.x) * sc + sh; v.y = (v.y >= 0.0f) ? v.y : 0.01f * v.y;
    v.z = bflo(a.y) * sc + sh; v.z = (v.z >= 0.0f) ? v.z : 0.01f * v.z;
    v.w = bfhi(a.y) * sc + sh; v.w = (v.w >= 0.0f) ? v.w : 0.01f * v.w;
    out[f] = v;
}

// ---------------------------------------------------------------------------
extern "C" void kernel_launch(void* const* d_in, const int* in_sizes, int n_in,
                              void* d_out, int out_size, void* d_ws, size_t ws_size,
                              hipStream_t stream) {
    const float* x   = (const float*)d_in[0];
    const float* xr  = (const float*)d_in[1];
    const float* ro  = (const float*)d_in[2];
    const float* wr  = (const float*)d_in[3];
    const float* gr  = (const float*)d_in[4];
    const float* br  = (const float*)d_in[5];
    const float* dw1 = (const float*)d_in[6];
    const float* pw1 = (const float*)d_in[7];
    const float* g1  = (const float*)d_in[8];
    const float* b1  = (const float*)d_in[9];
    const float* dw2 = (const float*)d_in[10];
    const float* pw2 = (const float*)d_in[11];
    const float* g2  = (const float*)d_in[12];
    const float* b2  = (const float*)d_in[13];

    unsigned short* WS = (unsigned short*)d_ws;
    unsigned short* y0 = WS;                  // 256 x HW bf16
    unsigned short* Z1 = WS + 3145728;        // 128 x HW bf16
    unsigned short* D  = WS + 4718592;        // 128 x HW bf16 (dw out, reused)
    unsigned short* Z2 = WS + 6291456;
    unsigned short* Z3 = WS + 7864320;
    unsigned short* W1h = WS + 9438720;       // 128x256 bf16 hi
    unsigned short* W1l = WS + 9471488;       // 128x256 bf16 lo
    unsigned short* W2h = WS + 9504256;       // 128x128
    unsigned short* W2l = WS + 9520640;
    unsigned short* W3h = WS + 9537024;
    unsigned short* W3l = WS + 9553408;
    // stat partials (384 x 256 fp32 = 384 KB) live in dead Z-slots:
    float* part1 = (float*)(WS + 6291456);    // Z2 slot (written later by pw2)
    float* part2 = (float*)WS;                // y0 slot (dead after pw1)
    float* part3 = (float*)WS;                // y0 slot (still dead)
    float* out = (float*)d_out;

    k_deform<<<dim3(8, 193), 256, 0, stream>>>(x, xr, ro, y0, wr, pw1, pw2,
                                               W1h, W1l, W2h, W2l, W3h, W3l);
    k_pw_mfma<256><<<dim3(384, 2), 256, 0, stream>>>(y0, W1h, W1l, Z1, part1);
    k_dw<<<1536, 256, 0, stream>>>(Z1, part1, gr, br, dw1, (ushort4*)D);
    k_pw_mfma<128><<<dim3(384, 2), 256, 0, stream>>>(D, W2h, W2l, Z2, part2);
    k_dw<<<1536, 256, 0, stream>>>(Z2, part2, g1, b1, dw2, (ushort4*)D);
    k_pw_mfma<128><<<dim3(384, 2), 256, 0, stream>>>(D, W3h, W3l, Z3, part3);
    k_final<<<1536, 256, 0, stream>>>(Z3, part3, g2, b2, (float4*)out);
}

// Round 5
// 146.827 us; speedup vs baseline: 2.8339x; 1.0389x over previous
//
#include <hip/hip_runtime.h>

#define HW    12288
#define Wimg  192
#define Himg  64
#define Wpad  194
#define Ppad  12804   // 66*194

typedef __attribute__((ext_vector_type(8))) __bf16 bf16x8;
typedef __attribute__((ext_vector_type(4))) float  f32x4;

// bf16 <-> fp32 helpers (RNE), header-independent
static __device__ __forceinline__ unsigned short f2bf(float f) {
    union { float f; unsigned int u; } v; v.f = f;
    unsigned int r = v.u + 0x7fffu + ((v.u >> 16) & 1u);
    return (unsigned short)(r >> 16);
}
static __device__ __forceinline__ float bf2f(unsigned short h) {
    union { unsigned int u; float f; } v; v.u = ((unsigned int)h) << 16;
    return v.f;
}
static __device__ __forceinline__ float bflo(unsigned int u) {
    union { unsigned int u; float f; } v; v.u = u << 16; return v.f;
}
static __device__ __forceinline__ float bfhi(unsigned int u) {
    union { unsigned int u; float f; } v; v.u = u & 0xffff0000u; return v.f;
}

// ---------------------------------------------------------------------------
// K1: deformable gather via LDS-staged windows (flat-space staging).
// Unchanged math (R15-R19 proven).  blockIdx.y==192 stripe does the weight
// prep (fp32 -> bf16 hi/lo split).
// ---------------------------------------------------------------------------
__global__ __launch_bounds__(256, 6) void k_deform(
    const float* __restrict__ x,     // 256 x HW
    const float* __restrict__ xr,    // HW
    const float* __restrict__ rout,  // 256 x 9
    unsigned short* __restrict__ y0, // 256 x HW (bf16)
    const float* __restrict__ wr,    // 128 x 256
    const float* __restrict__ pw1,   // 128 x 128
    const float* __restrict__ pw2,   // 128 x 128
    unsigned short* __restrict__ W1h, unsigned short* __restrict__ W1l,
    unsigned short* __restrict__ W2h, unsigned short* __restrict__ W2l,
    unsigned short* __restrict__ W3h, unsigned short* __restrict__ W3l)
{
    __shared__ unsigned short s_x[32][240];  // 3 window rows x stride 80

    const int cblk = blockIdx.x;     // 0..7   (fastest -> XCD id)
    const int tile = blockIdx.y;     // 0..191 deform, 192 = weight prep
    const int tid  = threadIdx.x;

    if (tile == 192) {
        const int base = cblk * 256 + tid;   // 0..2047
        #pragma unroll
        for (int k = 0; k < 32; ++k) {
            const int idx = base + k * 2048;
            float v;
            unsigned short *dh, *dl;
            if (idx < 32768)      { v = wr[idx];         dh = W1h + idx; dl = W1l + idx; }
            else if (idx < 49152) { int u = idx - 32768; v = pw1[u]; dh = W2h + u; dl = W2l + u; }
            else                  { int u = idx - 49152; v = pw2[u]; dh = W3h + u; dl = W3l + u; }
            unsigned short hh = f2bf(v);
            *dh = hh;
            *dl = f2bf(v - bf2f(hh));
        }
        return;
    }

    const int pl   = tid & 63;
    const int wv   = __builtin_amdgcn_readfirstlane(tid >> 6);
    const int h    = tile / 3;
    const int w0   = (tile - h * 3) * 64;
    const int w    = w0 + pl;
    const int gp   = h * Wimg + w;

    int   li[6];
    float gw[6][3];
    const float off = 3.0f / (1.0f + expf(-xr[gp]));

    #pragma unroll
    for (int t = 0; t < 6; ++t) {
        const int xo = (t & 1) ? 1 : -1;
        const int yo = (t >> 1) - 1;
        float ov  = off * (float)xo;
        int   iv  = yo * Wpad;
        int   pre = (h + 1) * Wpad + (w + 1) + xo + iv;
        float after = (float)(pre + iv) + ov;
        int fl = (int)floorf(ov);
        int ce = (int)ceilf(ov);
        int av_f  = min(max(pre + fl + iv, 0), Ppad - 1);
        int av_f1 = min(max(av_f + xo,    0), Ppad - 1);
        int av_c  = min(max(pre + ce + iv, 0), Ppad - 1);
        int av_c1 = min(max(av_c + xo,    0), Ppad - 1);
        float wf  = fabsf(after - (float)av_f);
        float wf1 = fabsf((float)av_f1 - after);
        float wc1 = fabsf(after - (float)av_c1);
        float wc  = fabsf((float)av_c - after);
        float s1 = wf  * (1.0f / Wpad);
        float s2 = wc1 * (1.0f / Wpad);
        int   i4[4] = { av_f, av_f1, av_c1, av_c };
        float w4[4] = { s1 * wf, s1 * wf1, s2 * wc1, s2 * wc };
        int b = min(min(i4[0], i4[1]), min(i4[2], i4[3]));
        const int base = (h + 1 + 2 * yo) * Wpad + w0 - 4;
        li[t] = (t >> 1) * 80 + min(max(b - base, 0), 71);
        #pragma unroll
        for (int s = 0; s < 3; ++s) {
            float ws = 0.0f;
            #pragma unroll
            for (int j = 0; j < 4; ++j)
                ws += (i4[j] == b + s) ? w4[j] : 0.0f;
            int av = b + s;
            int r  = av / Wpad;
            int cc = av - r * Wpad;
            bool inb = (r >= 1) && (r <= Himg) && (cc >= 1) && (cc <= Wimg);
            gw[t][s] = inb ? ws : 0.0f;
        }
    }

    // stage the 3x74 flat windows for the block's 32 channels (bf16)
    const int jj = tid;
    int  xoff = 0;
    bool valid = false;
    int  rr = 0, jcol = 0;
    if (jj < 222) {
        rr   = jj / 74;
        jcol = jj - rr * 74;
        const int flat = (h + 1 + 2 * (rr - 1)) * Wpad + w0 - 4 + jcol;
        if (flat >= 0 && flat < Ppad) {
            const int r = flat / Wpad;
            const int c = flat - r * Wpad;
            valid = (r >= 1) && (r <= Himg) && (c >= 1) && (c <= Wimg);
            xoff  = valid ? ((r - 1) * Wimg + (c - 1)) : 0;
        }
    }
    const float* xb = x + (size_t)(cblk * 32) * HW;
    for (int c = 0; c < 32; ++c) {
        if (jj < 222) {
            float v = valid ? xb[(size_t)c * HW + xoff] : 0.0f;
            s_x[c][rr * 80 + jcol] = f2bf(v);
        }
    }
    __syncthreads();

    const int c0l = wv * 8;
    #pragma unroll 2
    for (int i = 0; i < 8; ++i) {
        const int cl = c0l + i;
        const unsigned short* sxc = s_x[cl];
        const float* rc = rout + (cblk * 32 + cl) * 9;
        float acc = 0.0f;
        #pragma unroll
        for (int t = 0; t < 6; ++t) {
            float part = gw[t][0] * bf2f(sxc[li[t]])
                       + gw[t][1] * bf2f(sxc[li[t] + 1])
                       + gw[t][2] * bf2f(sxc[li[t] + 2]);
            const int k = 3 * (t >> 1) + ((t & 1) ? 2 : 0);
            acc += rc[k] * part;
        }
        y0[(size_t)(cblk * 32 + cl) * HW + gp] = f2bf(acc);
    }
}

// ---------------------------------------------------------------------------
// R25: MFMA pointwise GEMM.  Weight fragments hoisted to registers BEFORE the
// barrier (pure dwordx4 loads of pre-split bf16; L2 latency overlaps staging).
// Non-atomic per-block stat partials; consumers fold them.
// Block: 4 waves x (16 o x 32 px).  Grid (384 px-blocks, 2 o-blocks) = 768.
// ---------------------------------------------------------------------------
template <int CIN>
__global__ __launch_bounds__(256, 4) void k_pw_mfma(
    const unsigned short* __restrict__ Aact,  // CIN x HW (bf16)
    const unsigned short* __restrict__ Whi,   // 128 x CIN (bf16)
    const unsigned short* __restrict__ Wlo,   // 128 x CIN (bf16)
    unsigned short* __restrict__ Z,           // 128 x HW (bf16)
    float* __restrict__ part)                 // 384 x 256 {sum,sumsq} partials
{
    constexpr int KC = CIN / 32;
    constexpr int RS = CIN + 8;               // pad keeps b128 16B-aligned
    __shared__ __align__(16) unsigned short s_b[32][RS];

    const int tid = threadIdx.x;
    const int l   = tid & 63;
    const int wv  = tid >> 6;
    const int px0 = blockIdx.x * 32;
    const int o0  = blockIdx.y * 64;

    // ---- stage act tile transposed: s_b[p][c ^ (((p>>4)&3)<<3)] ----
    {
        const int cs  = tid >> 1;             // 0..127
        const int pxb = (tid & 1) << 4;       // 0 or 16
        const int swz = (tid & 1) << 3;       // (p>>4)&3 == tid&1 here
        #pragma unroll
        for (int it = 0; it < CIN / 128; ++it) {
            const int c = cs + it * 128;
            const uint4* src = (const uint4*)(Aact + (size_t)c * HW + px0 + pxb);
            uint4 u0 = src[0];
            uint4 u1 = src[1];
            const int sc = c ^ swz;
            unsigned int wd[8] = {u0.x, u0.y, u0.z, u0.w, u1.x, u1.y, u1.z, u1.w};
            #pragma unroll
            for (int e = 0; e < 8; ++e) {
                s_b[pxb + 2 * e    ][sc] = (unsigned short)(wd[e] & 0xffffu);
                s_b[pxb + 2 * e + 1][sc] = (unsigned short)(wd[e] >> 16);
            }
        }
    }

    // ---- hoist weight fragments into registers (overlaps staging/barrier) ----
    // A-frag layout: row m = l&15, k = (l>>4)*8 + j
    const int orow = o0 + wv * 16 + (l & 15);
    const unsigned short* whp = Whi + (size_t)orow * CIN + ((l >> 4) << 3);
    const unsigned short* wlp = Wlo + (size_t)orow * CIN + ((l >> 4) << 3);
    bf16x8 wh[KC], wl[KC];
    #pragma unroll
    for (int kc = 0; kc < KC; ++kc) {
        wh[kc] = *(const bf16x8*)(whp + kc * 32);
        wl[kc] = *(const bf16x8*)(wlp + kc * 32);
    }

    __syncthreads();

    // ---- MFMA K-loop (fully unrolled, weights in regs) ----
    f32x4 acc[2] = { {0.f, 0.f, 0.f, 0.f}, {0.f, 0.f, 0.f, 0.f} };
    const int prow = l & 15;
    const int kg8  = l >> 4;
    #pragma unroll
    for (int kc = 0; kc < KC; ++kc) {
        #pragma unroll
        for (int ip = 0; ip < 2; ++ip) {
            const int col = kc * 32 + (((kg8 ^ ip) & 3) << 3);
            bf16x8 bfr = *(const bf16x8*)&s_b[ip * 16 + prow][col];
            acc[ip] = __builtin_amdgcn_mfma_f32_16x16x32_bf16(wh[kc], bfr, acc[ip], 0, 0, 0);
            acc[ip] = __builtin_amdgcn_mfma_f32_16x16x32_bf16(wl[kc], bfr, acc[ip], 0, 0, 0);
        }
    }

    // ---- epilogue: store Z (bf16) + per-block partial BN stats (no atomics) ----
    // D layout: col = l&15 (px), row m = (l>>4)*4 + r  (m89-verified)
    float* pp = part + (size_t)blockIdx.x * 256;
    const int obase = o0 + wv * 16 + ((l >> 4) << 2);
    #pragma unroll
    for (int r = 0; r < 4; ++r) {
        const int ch = obase + r;
        float v0 = acc[0][r];
        float v1 = acc[1][r];
        Z[(size_t)ch * HW + px0 + prow]      = f2bf(v0);
        Z[(size_t)ch * HW + px0 + 16 + prow] = f2bf(v1);
        float s = v0 + v1;
        float q = v0 * v0 + v1 * v1;
        s += __shfl_xor(s, 1, 64);  q += __shfl_xor(q, 1, 64);
        s += __shfl_xor(s, 2, 64);  q += __shfl_xor(q, 2, 64);
        s += __shfl_xor(s, 4, 64);  q += __shfl_xor(q, 4, 64);
        s += __shfl_xor(s, 8, 64);  q += __shfl_xor(q, 8, 64);
        if (prow == 0) {
            pp[2 * ch]     = s;
            pp[2 * ch + 1] = q;
        }
    }
}

// ---------------------------------------------------------------------------
// R25: fused stats-fold + BN+LeakyReLU + depthwise 3x3 (zero pad), with the
// channel stripe LDS-staged via uint4 loads (was 18 scalar global loads per
// thread).  Block = 1024 px (5.33 rows) of one channel; stages 9 halo rows
// (3.6 KB), zero-filled OOB rows and zeroed pads so edge reads land on 0.
// ---------------------------------------------------------------------------
__global__ __launch_bounds__(256) void k_dw(
    const unsigned short* __restrict__ Zs,
    const float* __restrict__ part,  // 384 x 256 partials
    const float* __restrict__ g,
    const float* __restrict__ b,
    const float* __restrict__ dwgt,  // 128 x 9
    ushort4* __restrict__ D)
{
    __shared__ float rs[4], rq[4];
    __shared__ __align__(16) unsigned short s_z[9 * 200 + 8];  // 9 rows x (8 pad + 192)
    const int tid = threadIdx.x;
    const int bx  = blockIdx.x;
    const int c   = bx / 12;                  // 12 blocks per channel
    const int m   = bx - c * 12;
    const int g0  = m * 1024;                 // first px of this block
    const int r0  = g0 / Wimg;                // first output row (floor)

    // stage rows r0-1 .. r0+7 at s_z[rr*200 + 8 + col]; pads zeroed
    const unsigned short* zc = Zs + (size_t)c * HW;
    if (tid < 216) {
        const int rr = tid / 24;              // 0..8
        const int cc = (tid - rr * 24) * 8;   // col start (8 shorts / 16 B)
        const int gr = r0 - 1 + rr;
        uint4 u = make_uint4(0u, 0u, 0u, 0u);
        if (gr >= 0 && gr < Himg)
            u = *(const uint4*)(zc + (size_t)gr * Wimg + cc);
        *(uint4*)&s_z[rr * 200 + 8 + cc] = u;
    } else if (tid < 226) {
        // zero the 9 left-pads and the tail (each 8 shorts = 16 B)
        *(uint4*)&s_z[(tid - 216) * 200] = make_uint4(0u, 0u, 0u, 0u);
    }

    // fold this channel's partials
    float s = 0.0f, q = 0.0f;
    for (int bb = tid; bb < 384; bb += 256) {
        const float* pb = part + (size_t)bb * 256 + 2 * c;
        s += pb[0];
        q += pb[1];
    }
    #pragma unroll
    for (int off = 32; off > 0; off >>= 1) {
        s += __shfl_down(s, off, 64);
        q += __shfl_down(q, off, 64);
    }
    if ((tid & 63) == 0) { rs[tid >> 6] = s; rq[tid >> 6] = q; }
    __syncthreads();
    s = rs[0] + rs[1] + rs[2] + rs[3];
    q = rq[0] + rq[1] + rq[2] + rq[3];

    const float mu  = s * (1.0f / HW);
    const float var = q * (1.0f / HW) - mu * mu;
    const float sc  = g[c] * rsqrtf(var + 1e-5f);
    const float sh  = b[c] - mu * sc;

    float wk[9];
    #pragma unroll
    for (int k = 0; k < 9; ++k) wk[k] = dwgt[c * 9 + k];

    const int gg = g0 + tid * 4;              // first of 4 px
    const int h  = gg / Wimg;
    const int w0 = gg - h * Wimg;
    const int lr = h - (r0 - 1);              // local row in s_z (1..7)

    float v[3][6];
    #pragma unroll
    for (int ky = 0; ky < 3; ++ky) {
        const int hh  = h + ky - 1;
        const bool rin = (hh >= 0) && (hh < Himg);
        const unsigned short* sr = &s_z[(lr - 1 + ky) * 200 + 7 + w0];
        #pragma unroll
        for (int j = 0; j < 6; ++j) {
            const int ww = w0 - 1 + j;
            const bool in = rin && (ww >= 0) && (ww < Wimg);
            float z = bf2f(sr[j]);            // staged zeros make OOB reads safe
            float y = z * sc + sh;
            y = (y >= 0.0f) ? y : 0.01f * y;
            v[ky][j] = in ? y : 0.0f;
        }
    }

    ushort4 o;
    float oo[4];
    #pragma unroll
    for (int j = 0; j < 4; ++j) {
        float a = 0.0f;
        #pragma unroll
        for (int ky = 0; ky < 3; ++ky)
            #pragma unroll
            for (int kx = 0; kx < 3; ++kx)
                a += wk[ky * 3 + kx] * v[ky][j + kx];
        oo[j] = a;
    }
    o.x = f2bf(oo[0]); o.y = f2bf(oo[1]); o.z = f2bf(oo[2]); o.w = f2bf(oo[3]);
    D[bx * 256 + tid] = o;
}

// ---------------------------------------------------------------------------
// Fused stats-fold + BN+LeakyReLU, fp32 out.  grid = 1536.
// ---------------------------------------------------------------------------
__global__ __launch_bounds__(256) void k_final(
    const unsigned short* __restrict__ Zs,
    const float* __restrict__ part,  // 384 x 256 partials
    const float* __restrict__ g,
    const float* __restrict__ b,
    float4* __restrict__ out)
{
    __shared__ float rs[4], rq[4];
    const int tid = threadIdx.x;
    const int c   = blockIdx.x / 12;          // 12 blocks per channel

    float s = 0.0f, q = 0.0f;
    for (int bb = tid; bb < 384; bb += 256) {
        const float* pb = part + (size_t)bb * 256 + 2 * c;
        s += pb[0];
        q += pb[1];
    }
    #pragma unroll
    for (int off = 32; off > 0; off >>= 1) {
        s += __shfl_down(s, off, 64);
        q += __shfl_down(q, off, 64);
    }
    if ((tid & 63) == 0) { rs[tid >> 6] = s; rq[tid >> 6] = q; }
    __syncthreads();
    s = rs[0] + rs[1] + rs[2] + rs[3];
    q = rq[0] + rq[1] + rq[2] + rq[3];

    const float mu  = s * (1.0f / HW);
    const float var = q * (1.0f / HW) - mu * mu;
    const float sc  = g[c] * rsqrtf(var + 1e-5f);
    const float sh  = b[c] - mu * sc;

    const int f = blockIdx.x * 256 + tid;
    uint2 a = ((const uint2*)Zs)[f];
    float4 v;
    v.x = bflo(a.x) * sc + sh; v.x = (v.x >= 0.0f) ? v.x : 0.01f * v.x;
    v.y = bfhi(a.x) * sc + sh; v.y = (v.y >= 0.0f) ? v.y : 0.01f * v.y;
    v.z = bflo(a.y) * sc + sh; v.z = (v.z >= 0.0f) ? v.z : 0.01f * v.z;
    v.w = bfhi(a.y) * sc + sh; v.w = (v.w >= 0.0f) ? v.w : 0.01f * v.w;
    out[f] = v;
}

// ---------------------------------------------------------------------------
extern "C" void kernel_launch(void* const* d_in, const int* in_sizes, int n_in,
                              void* d_out, int out_size, void* d_ws, size_t ws_size,
                              hipStream_t stream) {
    const float* x   = (const float*)d_in[0];
    const float* xr  = (const float*)d_in[1];
    const float* ro  = (const float*)d_in[2];
    const float* wr  = (const float*)d_in[3];
    const float* gr  = (const float*)d_in[4];
    const float* br  = (const float*)d_in[5];
    const float* dw1 = (const float*)d_in[6];
    const float* pw1 = (const float*)d_in[7];
    const float* g1  = (const float*)d_in[8];
    const float* b1  = (const float*)d_in[9];
    const float* dw2 = (const float*)d_in[10];
    const float* pw2 = (const float*)d_in[11];
    const float* g2  = (const float*)d_in[12];
    const float* b2  = (const float*)d_in[13];

    unsigned short* WS = (unsigned short*)d_ws;
    unsigned short* y0 = WS;                  // 256 x HW bf16
    unsigned short* Z1 = WS + 3145728;        // 128 x HW bf16
    unsigned short* D  = WS + 4718592;        // 128 x HW bf16 (dw out, reused)
    unsigned short* Z2 = WS + 6291456;
    unsigned short* Z3 = WS + 7864320;
    unsigned short* W1h = WS + 9438720;       // 128x256 bf16 hi
    unsigned short* W1l = WS + 9471488;       // 128x256 bf16 lo
    unsigned short* W2h = WS + 9504256;       // 128x128
    unsigned short* W2l = WS + 9520640;
    unsigned short* W3h = WS + 9537024;
    unsigned short* W3l = WS + 9553408;
    // stat partials (384 x 256 fp32 = 384 KB) live in dead Z-slots:
    float* part1 = (float*)(WS + 6291456);    // Z2 slot (written later by pw2)
    float* part2 = (float*)WS;                // y0 slot (dead after pw1)
    float* part3 = (float*)WS;                // y0 slot (still dead)
    float* out = (float*)d_out;

    k_deform<<<dim3(8, 193), 256, 0, stream>>>(x, xr, ro, y0, wr, pw1, pw2,
                                               W1h, W1l, W2h, W2l, W3h, W3l);
    k_pw_mfma<256><<<dim3(384, 2), 256, 0, stream>>>(y0, W1h, W1l, Z1, part1);
    k_dw<<<1536, 256, 0, stream>>>(Z1, part1, gr, br, dw1, (ushort4*)D);
    k_pw_mfma<128><<<dim3(384, 2), 256, 0, stream>>>(D, W2h, W2l, Z2, part2);
    k_dw<<<1536, 256, 0, stream>>>(Z2, part2, g1, b1, dw2, (ushort4*)D);
    k_pw_mfma<128><<<dim3(384, 2), 256, 0, stream>>>(D, W3h, W3l, Z3, part3);
    k_final<<<1536, 256, 0, stream>>>(Z3, part3, g2, b2, (float4*)out);
}